// Round 1
// baseline (943.156 us; speedup 1.0000x reference)
//
#include <hip/hip_runtime.h>

typedef unsigned short u16;
typedef unsigned int u32;
typedef __attribute__((ext_vector_type(8))) short short8;
typedef __attribute__((ext_vector_type(4))) float f32x4;
typedef __attribute__((ext_vector_type(4))) int i32x4;

#define SEQ 2048
#define DIM 1024
#define NEXP 8
#define MDIM 4096

__device__ __forceinline__ u16 f2bf(float f) {
  union { float f; u32 u; } v; v.f = f;
  u32 r = (v.u + 0x7fffu + ((v.u >> 16) & 1u)) >> 16;
  return (u16)r;
}
__device__ __forceinline__ float bf2f(u16 h) {
  union { float f; u32 u; } v; v.u = ((u32)h) << 16;
  return v.f;
}

// ---------------- x fp32 -> bf16 ----------------
__global__ __launch_bounds__(256) void cvt_x_kernel(const float4* __restrict__ x,
                                                    uint2* __restrict__ xb) {
  int i = blockIdx.x * 256 + threadIdx.x;   // over SEQ*DIM/4
  float4 v = x[i];
  uint2 o;
  o.x = (u32)f2bf(v.x) | ((u32)f2bf(v.y) << 16);
  o.y = (u32)f2bf(v.z) | ((u32)f2bf(v.w) << 16);
  xb[i] = o;
}

// ---------------- gate: logits, softmax-top2, renorm ----------------
__global__ __launch_bounds__(256) void gate_kernel(const float* __restrict__ x,
                                                   const float* __restrict__ Wgate,
                                                   const float* __restrict__ bgate,
                                                   int* __restrict__ list_tok,
                                                   float* __restrict__ list_w,
                                                   int* __restrict__ cnt) {
  int s = blockIdx.x, t = threadIdx.x;
  float acc[8];
#pragma unroll
  for (int e = 0; e < 8; ++e) acc[e] = 0.f;
  float4 xv = ((const float4*)(x + (size_t)s * DIM))[t];
  const float4* wg = (const float4*)(Wgate + 32 * t);  // rows 4t..4t+3, 8 floats each
#pragma unroll
  for (int j = 0; j < 4; ++j) {
    float xs = (j == 0) ? xv.x : (j == 1) ? xv.y : (j == 2) ? xv.z : xv.w;
    float4 wa = wg[j * 2], wb = wg[j * 2 + 1];
    acc[0] += xs * wa.x; acc[1] += xs * wa.y; acc[2] += xs * wa.z; acc[3] += xs * wa.w;
    acc[4] += xs * wb.x; acc[5] += xs * wb.y; acc[6] += xs * wb.z; acc[7] += xs * wb.w;
  }
#pragma unroll
  for (int e = 0; e < 8; ++e) {
#pragma unroll
    for (int off = 32; off > 0; off >>= 1) acc[e] += __shfl_down(acc[e], off);
  }
  __shared__ float part[4][8];
  int lane = t & 63, wid = t >> 6;
  if (lane == 0) {
#pragma unroll
    for (int e = 0; e < 8; ++e) part[wid][e] = acc[e];
  }
  __syncthreads();
  if (t == 0) {
    float lg[8];
#pragma unroll
    for (int e = 0; e < 8; ++e)
      lg[e] = part[0][e] + part[1][e] + part[2][e] + part[3][e] + bgate[e];
    int i0 = 0;
    for (int e = 1; e < 8; ++e) if (lg[e] > lg[i0]) i0 = e;   // strict > : tie -> lower idx
    int i1 = (i0 == 0) ? 1 : 0;
    for (int e = 0; e < 8; ++e) if (e != i0 && lg[e] > lg[i1]) i1 = e;
    // renormalized top-2 softmax weights
    float e1v = __expf(lg[i1] - lg[i0]);
    float w0 = 1.f / (1.f + e1v);
    float w1 = e1v / (1.f + e1v);
    int p0 = atomicAdd(&cnt[i0], 1);
    list_tok[i0 * SEQ + p0] = s; list_w[i0 * SEQ + p0] = w0;
    int p1 = atomicAdd(&cnt[i1], 1);
    list_tok[i1 * SEQ + p1] = s; list_w[i1 * SEQ + p1] = w1;
  }
}

__global__ void scan_kernel(const int* __restrict__ cnt, int* __restrict__ basev) {
  if (threadIdx.x == 0 && blockIdx.x == 0) {
    int a = 0;
    for (int e = 0; e < 8; ++e) { basev[e] = a; a += cnt[e]; }
  }
}

__global__ __launch_bounds__(256) void compact_kernel(const int* __restrict__ cnt,
                                                      const int* __restrict__ basev,
                                                      const int* __restrict__ list_tok,
                                                      const float* __restrict__ list_w,
                                                      int* __restrict__ tok_c,
                                                      float* __restrict__ w_c) {
  int e = blockIdx.x;
  int n = cnt[e], b0 = basev[e];
  for (int i = threadIdx.x; i < n; i += 256) {
    tok_c[b0 + i] = list_tok[e * SEQ + i];
    w_c[b0 + i]   = list_w[e * SEQ + i];
  }
}

// ---------------- GEMM 1/2: [cnt_e x 1024] x [1024 x 4096] ----------------
// mode 0: hg = swish(x*Wg + bg)     mode 1: hg = hg * (x*W1 + b1)
__global__ __launch_bounds__(256) void gemm12_kernel(
    const u16* __restrict__ xb, const float* __restrict__ W,
    const float* __restrict__ bias, const int* __restrict__ tok_c,
    const int* __restrict__ basev, const int* __restrict__ cnt,
    u16* __restrict__ hg, int mode) {
  int b = blockIdx.x;
  int nt = b & 31, tt = (b >> 5) & 15, e = b >> 9;
  int cntE = cnt[e];
  int m0 = tt * 128;
  if (m0 >= cntE) return;
  int baseE = basev[e];
  int n0 = nt * 128;
  const float* We = W + (size_t)e * DIM * MDIM;

  __shared__ u16 Al[128 * 72];   // [row][k], pitch 72 (144B, 16B aligned)
  __shared__ u16 Bl[128 * 72];   // [n][k] transposed, pitch 72

  int tid = threadIdx.x;
  int lane = tid & 63, wid = tid >> 6;
  int wm = (wid >> 1) * 64, wn = (wid & 1) * 64;
  int q = lane >> 4, lr = lane & 15;

  f32x4 acc[4][4];
#pragma unroll
  for (int i = 0; i < 4; ++i)
#pragma unroll
    for (int j = 0; j < 4; ++j) acc[i][j] = (f32x4){0.f, 0.f, 0.f, 0.f};

  const u16* arow[4];
  int ack[4];
#pragma unroll
  for (int i = 0; i < 4; ++i) {
    int c = i * 256 + tid;
    int r = c >> 3, ck = c & 7;
    int gm = m0 + r;
    int src = baseE + (gm < cntE ? gm : cntE - 1);
    arow[i] = xb + (size_t)tok_c[src] * DIM + ck * 8;
    ack[i] = r * 72 + ck * 8;
  }

  for (int k0 = 0; k0 < DIM; k0 += 64) {
    __syncthreads();
#pragma unroll
    for (int i = 0; i < 4; ++i)
      *(i32x4*)&Al[ack[i]] = *(const i32x4*)(arow[i] + k0);
#pragma unroll 4
    for (int i = 0; i < 16; ++i) {
      int w = i * 256 + tid;
      int n = w & 127, kk = (w >> 7) * 2;
      const float* src = We + (size_t)(k0 + kk) * MDIM + n0 + n;
      float f0 = src[0], f1 = src[MDIM];
      *(u32*)&Bl[n * 72 + kk] = (u32)f2bf(f0) | ((u32)f2bf(f1) << 16);
    }
    __syncthreads();
#pragma unroll
    for (int ks = 0; ks < 64; ks += 32) {
      short8 af[4], bf[4];
#pragma unroll
      for (int fm = 0; fm < 4; ++fm)
        af[fm] = *(const short8*)&Al[(wm + fm * 16 + lr) * 72 + ks + q * 8];
#pragma unroll
      for (int fn = 0; fn < 4; ++fn)
        bf[fn] = *(const short8*)&Bl[(wn + fn * 16 + lr) * 72 + ks + q * 8];
#pragma unroll
      for (int fm = 0; fm < 4; ++fm)
#pragma unroll
        for (int fn = 0; fn < 4; ++fn)
          acc[fm][fn] = __builtin_amdgcn_mfma_f32_16x16x32_bf16(af[fm], bf[fn], acc[fm][fn], 0, 0, 0);
    }
  }

  const float* be = bias + (size_t)e * MDIM + n0;
#pragma unroll
  for (int fm = 0; fm < 4; ++fm) {
#pragma unroll
    for (int r = 0; r < 4; ++r) {
      int lm = wm + fm * 16 + q * 4 + r;
      int gm = m0 + lm;
      if (gm < cntE) {
        u16* row = hg + (size_t)(baseE + gm) * MDIM + n0;
#pragma unroll
        for (int fn = 0; fn < 4; ++fn) {
          int col = wn + fn * 16 + lr;
          float v = acc[fm][fn][r] + be[col];
          if (mode == 0) {
            v = v / (1.f + __expf(-v));   // swish
            row[col] = f2bf(v);
          } else {
            row[col] = f2bf(bf2f(row[col]) * v);
          }
        }
      }
    }
  }
}

// ---------------- GEMM 3: [cnt_e x 4096] x [4096 x 1024] -> scatter-add ----------------
__global__ __launch_bounds__(256) void gemm3_kernel(
    const u16* __restrict__ hg, const float* __restrict__ W2,
    const float* __restrict__ b2, const int* __restrict__ tok_c,
    const float* __restrict__ w_c, const int* __restrict__ basev,
    const int* __restrict__ cnt, float* __restrict__ out) {
  int b = blockIdx.x;
  int nt = b & 7, tt = (b >> 3) & 31, e = b >> 8;
  int cntE = cnt[e];
  int m0 = tt * 64;
  if (m0 >= cntE) return;
  int baseE = basev[e];
  int n0 = nt * 128;
  const float* We = W2 + (size_t)e * MDIM * DIM;

  __shared__ u16 Al[64 * 72];
  __shared__ u16 Bl[128 * 72];

  int tid = threadIdx.x;
  int lane = tid & 63, wid = tid >> 6;
  int wm = (wid >> 1) * 32, wn = (wid & 1) * 64;
  int q = lane >> 4, lr = lane & 15;

  f32x4 acc[2][4];
#pragma unroll
  for (int i = 0; i < 2; ++i)
#pragma unroll
    for (int j = 0; j < 4; ++j) acc[i][j] = (f32x4){0.f, 0.f, 0.f, 0.f};

  const u16* arow[2];
  int ack[2];
#pragma unroll
  for (int i = 0; i < 2; ++i) {
    int c = i * 256 + tid;
    int r = c >> 3, ck = c & 7;
    int gm = m0 + r;
    int src = baseE + (gm < cntE ? gm : cntE - 1);
    arow[i] = hg + (size_t)src * MDIM + ck * 8;
    ack[i] = r * 72 + ck * 8;
  }

  for (int k0 = 0; k0 < MDIM; k0 += 64) {
    __syncthreads();
#pragma unroll
    for (int i = 0; i < 2; ++i)
      *(i32x4*)&Al[ack[i]] = *(const i32x4*)(arow[i] + k0);
#pragma unroll 4
    for (int i = 0; i < 16; ++i) {
      int w = i * 256 + tid;
      int n = w & 127, kk = (w >> 7) * 2;
      const float* src = We + (size_t)(k0 + kk) * DIM + n0 + n;
      float f0 = src[0], f1 = src[DIM];
      *(u32*)&Bl[n * 72 + kk] = (u32)f2bf(f0) | ((u32)f2bf(f1) << 16);
    }
    __syncthreads();
#pragma unroll
    for (int ks = 0; ks < 64; ks += 32) {
      short8 af[2], bf[4];
#pragma unroll
      for (int fm = 0; fm < 2; ++fm)
        af[fm] = *(const short8*)&Al[(wm + fm * 16 + lr) * 72 + ks + q * 8];
#pragma unroll
      for (int fn = 0; fn < 4; ++fn)
        bf[fn] = *(const short8*)&Bl[(wn + fn * 16 + lr) * 72 + ks + q * 8];
#pragma unroll
      for (int fm = 0; fm < 2; ++fm)
#pragma unroll
        for (int fn = 0; fn < 4; ++fn)
          acc[fm][fn] = __builtin_amdgcn_mfma_f32_16x16x32_bf16(af[fm], bf[fn], acc[fm][fn], 0, 0, 0);
    }
  }

  const float* be = b2 + (size_t)e * DIM + n0;
#pragma unroll
  for (int fm = 0; fm < 2; ++fm) {
#pragma unroll
    for (int r = 0; r < 4; ++r) {
      int lm = wm + fm * 16 + q * 4 + r;
      int gm = m0 + lm;
      if (gm < cntE) {
        float wgt = w_c[baseE + gm];
        int tok = tok_c[baseE + gm];
        float* orow = out + (size_t)tok * DIM + n0;
#pragma unroll
        for (int fn = 0; fn < 4; ++fn) {
          int col = wn + fn * 16 + lr;
          atomicAdd(&orow[col], wgt * (acc[fm][fn][r] + be[col]));
        }
      }
    }
  }
}

extern "C" void kernel_launch(void* const* d_in, const int* in_sizes, int n_in,
                              void* d_out, int out_size, void* d_ws, size_t ws_size,
                              hipStream_t stream) {
  const float* x     = (const float*)d_in[0];
  const float* Wgate = (const float*)d_in[1];
  const float* bgate = (const float*)d_in[2];
  const float* Wg    = (const float*)d_in[3];
  const float* bg    = (const float*)d_in[4];
  const float* W1    = (const float*)d_in[5];
  const float* b1    = (const float*)d_in[6];
  const float* W2    = (const float*)d_in[7];
  const float* b2    = (const float*)d_in[8];
  float* out = (float*)d_out;

  char* ws = (char*)d_ws;
  // workspace layout (total ~37.9 MB)
  u16*   xb    = (u16*)(ws + 0);                 // SEQ*DIM bf16            = 4194304 B
  u16*   hg    = (u16*)(ws + 4194304);           // 4096*MDIM bf16          = 33554432 B
  int*   tokc  = (int*)(ws + 37748736);          // 4096 int
  float* wc    = (float*)(ws + 37765120);        // 4096 float
  int*   ltok  = (int*)(ws + 37781504);          // 8*2048 int
  float* lw    = (float*)(ws + 37847040);        // 8*2048 float
  int*   cnt   = (int*)(ws + 37912576);          // 8 int
  int*   basev = (int*)(ws + 37912608);          // 8 int

  hipMemsetAsync(d_out, 0, (size_t)out_size * sizeof(float), stream);
  hipMemsetAsync(cnt, 0, 64, stream);

  cvt_x_kernel<<<SEQ * DIM / 4 / 256, 256, 0, stream>>>((const float4*)x, (uint2*)xb);
  gate_kernel<<<SEQ, 256, 0, stream>>>(x, Wgate, bgate, ltok, lw, cnt);
  scan_kernel<<<1, 64, 0, stream>>>(cnt, basev);
  compact_kernel<<<NEXP, 256, 0, stream>>>(cnt, basev, ltok, lw, tokc, wc);

  // GEMM1: swish(x*Wg+bg) -> hg
  gemm12_kernel<<<NEXP * 16 * 32, 256, 0, stream>>>(xb, Wg, bg, tokc, basev, cnt, hg, 0);
  // GEMM2: hg *= (x*W1+b1)
  gemm12_kernel<<<NEXP * 16 * 32, 256, 0, stream>>>(xb, W1, b1, tokc, basev, cnt, hg, 1);
  // GEMM3: out += w * (hg*W2 + b2)
  gemm3_kernel<<<NEXP * 32 * 8, 256, 0, stream>>>(hg, W2, b2, tokc, wc, basev, cnt, out);
}

// Round 2
// 749.164 us; speedup vs baseline: 1.2589x; 1.2589x over previous
//
#include <hip/hip_runtime.h>

typedef unsigned short u16;
typedef unsigned int u32;
typedef __attribute__((ext_vector_type(8))) short short8;
typedef __attribute__((ext_vector_type(4))) float f32x4;
typedef __attribute__((ext_vector_type(4))) int i32x4;

#define SEQ 2048
#define DIM 1024
#define NEXP 8
#define MDIM 4096

__device__ __forceinline__ u16 f2bf(float f) {
  union { float f; u32 u; } v; v.f = f;
  u32 r = (v.u + 0x7fffu + ((v.u >> 16) & 1u)) >> 16;
  return (u16)r;
}
__device__ __forceinline__ float bf2f(u16 h) {
  union { float f; u32 u; } v; v.u = ((u32)h) << 16;
  return v.f;
}

// async global->LDS 16B copy (CK-style addrspace casts; LDS dst = wave-uniform base + lane*16)
__device__ __forceinline__ void async_copy16(const void* g, void* l) {
  __builtin_amdgcn_global_load_lds(
      (const __attribute__((address_space(1))) unsigned int*)g,
      (__attribute__((address_space(3))) unsigned int*)(u32)(unsigned long long)l,
      16, 0, 0);
}

// ---------------- x fp32 -> bf16 ----------------
__global__ __launch_bounds__(256) void cvt_x_kernel(const float4* __restrict__ x,
                                                    uint2* __restrict__ xb) {
  int i = blockIdx.x * 256 + threadIdx.x;
  float4 v = x[i];
  uint2 o;
  o.x = (u32)f2bf(v.x) | ((u32)f2bf(v.y) << 16);
  o.y = (u32)f2bf(v.z) | ((u32)f2bf(v.w) << 16);
  xb[i] = o;
}

// ---------------- weight fp32 [E][K][N] -> bf16 [E][N][K] (gather-transpose) ----------------
__global__ __launch_bounds__(256) void wconv_kernel(const float* __restrict__ in,
                                                    u16* __restrict__ out,
                                                    int K, int lgN, int lgCPE) {
  u32 c = blockIdx.x * 256 + threadIdx.x;
  u32 e = c >> lgCPE;
  u32 r = c & ((1u << lgCPE) - 1u);
  u32 kc = r >> lgN;
  u32 n = r & ((1u << lgN) - 1u);
  u32 N = 1u << lgN;
  const float* src = in + ((size_t)e << (lgCPE + 3)) + (size_t)(kc * 8) * N + n;
  float f[8];
#pragma unroll
  for (int j = 0; j < 8; ++j) f[j] = src[(size_t)j * N];
  u32 o[4];
#pragma unroll
  for (int j = 0; j < 4; ++j) o[j] = (u32)f2bf(f[2 * j]) | ((u32)f2bf(f[2 * j + 1]) << 16);
  u16* dst = out + ((size_t)e << (lgCPE + 3)) + (size_t)n * K + kc * 8;
  *(i32x4*)dst = *(const i32x4*)o;
}

// ---------------- gate ----------------
__global__ __launch_bounds__(256) void gate_kernel(const float* __restrict__ x,
                                                   const float* __restrict__ Wgate,
                                                   const float* __restrict__ bgate,
                                                   int* __restrict__ list_tok,
                                                   float* __restrict__ list_w,
                                                   int* __restrict__ cnt,
                                                   int* __restrict__ tki,
                                                   float* __restrict__ tkw) {
  int s = blockIdx.x, t = threadIdx.x;
  float acc[8];
#pragma unroll
  for (int e = 0; e < 8; ++e) acc[e] = 0.f;
  float4 xv = ((const float4*)(x + (size_t)s * DIM))[t];
  const float4* wg = (const float4*)(Wgate + 32 * t);
#pragma unroll
  for (int j = 0; j < 4; ++j) {
    float xs = (j == 0) ? xv.x : (j == 1) ? xv.y : (j == 2) ? xv.z : xv.w;
    float4 wa = wg[j * 2], wb = wg[j * 2 + 1];
    acc[0] += xs * wa.x; acc[1] += xs * wa.y; acc[2] += xs * wa.z; acc[3] += xs * wa.w;
    acc[4] += xs * wb.x; acc[5] += xs * wb.y; acc[6] += xs * wb.z; acc[7] += xs * wb.w;
  }
#pragma unroll
  for (int e = 0; e < 8; ++e) {
#pragma unroll
    for (int off = 32; off > 0; off >>= 1) acc[e] += __shfl_down(acc[e], off);
  }
  __shared__ float part[4][8];
  int lane = t & 63, wid = t >> 6;
  if (lane == 0) {
#pragma unroll
    for (int e = 0; e < 8; ++e) part[wid][e] = acc[e];
  }
  __syncthreads();
  if (t == 0) {
    float lg[8];
#pragma unroll
    for (int e = 0; e < 8; ++e)
      lg[e] = part[0][e] + part[1][e] + part[2][e] + part[3][e] + bgate[e];
    int i0 = 0;
    for (int e = 1; e < 8; ++e) if (lg[e] > lg[i0]) i0 = e;
    int i1 = (i0 == 0) ? 1 : 0;
    for (int e = 0; e < 8; ++e) if (e != i0 && lg[e] > lg[i1]) i1 = e;
    float e1v = __expf(lg[i1] - lg[i0]);
    float w0 = 1.f / (1.f + e1v);
    float w1 = e1v / (1.f + e1v);
    int p0 = atomicAdd(&cnt[i0], 1);
    list_tok[i0 * SEQ + p0] = s; list_w[i0 * SEQ + p0] = w0;
    int p1 = atomicAdd(&cnt[i1], 1);
    list_tok[i1 * SEQ + p1] = s; list_w[i1 * SEQ + p1] = w1;
    tki[2 * s] = i0; tki[2 * s + 1] = i1;
    tkw[2 * s] = w0; tkw[2 * s + 1] = w1;
  }
}

__global__ void scan_kernel(const int* __restrict__ cnt, int* __restrict__ basev) {
  if (threadIdx.x == 0 && blockIdx.x == 0) {
    int a = 0;
    for (int e = 0; e < 8; ++e) { basev[e] = a; a += cnt[e]; }
  }
}

__global__ __launch_bounds__(256) void compact_kernel(const int* __restrict__ cnt,
                                                      const int* __restrict__ basev,
                                                      const int* __restrict__ list_tok,
                                                      const float* __restrict__ list_w,
                                                      int* __restrict__ tok_c,
                                                      float* __restrict__ w_c) {
  int e = blockIdx.x;
  int n = cnt[e], b0 = basev[e];
  for (int i = threadIdx.x; i < n; i += 256) {
    tok_c[b0 + i] = list_tok[e * SEQ + i];
    w_c[b0 + i]   = list_w[e * SEQ + i];
  }
}

// ---------------- out = w0*b2[i0] + w1*b2[i1] ----------------
__global__ __launch_bounds__(256) void outinit_kernel(const int* __restrict__ tki,
                                                      const float* __restrict__ tkw,
                                                      const float* __restrict__ b2,
                                                      float* __restrict__ out) {
  int s = blockIdx.x, t = threadIdx.x;
  int i0 = tki[2 * s], i1 = tki[2 * s + 1];
  float w0 = tkw[2 * s], w1 = tkw[2 * s + 1];
  float4 a = ((const float4*)(b2 + (size_t)i0 * DIM))[t];
  float4 b = ((const float4*)(b2 + (size_t)i1 * DIM))[t];
  float4 o;
  o.x = w0 * a.x + w1 * b.x; o.y = w0 * a.y + w1 * b.y;
  o.z = w0 * a.z + w1 * b.z; o.w = w0 * a.w + w1 * b.w;
  ((float4*)(out + (size_t)s * DIM))[t] = o;
}

// ---------------- fused up-proj: hg = w * (swish(x*Wg+bg) .* (x*W1+b1)), bf16 ----------------
// 128x128 tile, BK=64, global_load_lds staging with XOR-8 chunk swizzle.
__global__ __launch_bounds__(256) void gemm_up_kernel(
    const u16* __restrict__ xb, const u16* __restrict__ Wgt, const u16* __restrict__ W1t,
    const float* __restrict__ bg, const float* __restrict__ b1,
    const int* __restrict__ tok_c, const float* __restrict__ w_c,
    const int* __restrict__ basev, const int* __restrict__ cnt,
    u16* __restrict__ hg) {
  int b = blockIdx.x;
  int nt = b & 31, tt = (b >> 5) & 15, e = b >> 9;
  int cntE = cnt[e];
  int m0 = tt * 128;
  if (m0 >= cntE) return;
  int baseE = basev[e];
  int n0 = nt * 128;

  __shared__ u16 Al[128 * 64];
  __shared__ u16 Bgl[128 * 64];
  __shared__ u16 B1l[128 * 64];

  int tid = threadIdx.x;
  int lane = tid & 63, wid = tid >> 6;
  int wm = (wid >> 1) * 64, wn = (wid & 1) * 64;
  int q = lane >> 4, lr = lane & 15;

  const u16* Wge = Wgt + (size_t)e * MDIM * DIM;
  const u16* W1e = W1t + (size_t)e * MDIM * DIM;

  // staging descriptors: idx = i*256+tid; row r = idx>>3; seg s = idx&7; global chunk = s ^ (r&7)
  u32 aoff[4], boff[4];
  int sseg = tid & 7;
#pragma unroll
  for (int i = 0; i < 4; ++i) {
    int r = (i * 256 + tid) >> 3;
    int c = sseg ^ (r & 7);
    int gm = m0 + r; if (gm >= cntE) gm = cntE - 1;
    aoff[i] = (u32)((tok_c[baseE + gm] * DIM + c * 8) * 2);
    boff[i] = (u32)(((n0 + r) * DIM + c * 8) * 2);
  }

  f32x4 accg[4][4], acc1[4][4];
#pragma unroll
  for (int i = 0; i < 4; ++i)
#pragma unroll
    for (int j = 0; j < 4; ++j) { accg[i][j] = (f32x4){0,0,0,0}; acc1[i][j] = (f32x4){0,0,0,0}; }

  for (int k0 = 0; k0 < DIM; k0 += 64) {
    __syncthreads();
#pragma unroll
    for (int i = 0; i < 4; ++i) {
      int ldso = i * 2048 + tid * 8;   // u16 units
      async_copy16((const char*)xb + aoff[i] + k0 * 2, &Al[ldso]);
      async_copy16((const char*)Wge + boff[i] + k0 * 2, &Bgl[ldso]);
      async_copy16((const char*)W1e + boff[i] + k0 * 2, &B1l[ldso]);
    }
    __syncthreads();
#pragma unroll
    for (int ks = 0; ks < 64; ks += 32) {
      short8 af[4], bgf[4], b1f[4];
      int j = (ks >> 3) + q;
#pragma unroll
      for (int f = 0; f < 4; ++f) {
        int r = wm + f * 16 + lr;
        af[f] = *(const short8*)&Al[r * 64 + ((j ^ (r & 7)) * 8)];
      }
#pragma unroll
      for (int f = 0; f < 4; ++f) {
        int r = wn + f * 16 + lr;
        int o = r * 64 + ((j ^ (r & 7)) * 8);
        bgf[f] = *(const short8*)&Bgl[o];
        b1f[f] = *(const short8*)&B1l[o];
      }
#pragma unroll
      for (int fm = 0; fm < 4; ++fm)
#pragma unroll
        for (int fn = 0; fn < 4; ++fn) {
          accg[fm][fn] = __builtin_amdgcn_mfma_f32_16x16x32_bf16(af[fm], bgf[fn], accg[fm][fn], 0, 0, 0);
          acc1[fm][fn] = __builtin_amdgcn_mfma_f32_16x16x32_bf16(af[fm], b1f[fn], acc1[fm][fn], 0, 0, 0);
        }
    }
  }

  const float* bge = bg + (size_t)e * MDIM + n0;
  const float* b1e = b1 + (size_t)e * MDIM + n0;
#pragma unroll
  for (int fm = 0; fm < 4; ++fm) {
#pragma unroll
    for (int rr = 0; rr < 4; ++rr) {
      int lm = wm + fm * 16 + q * 4 + rr;
      int gm = m0 + lm;
      if (gm < cntE) {
        float w = w_c[baseE + gm];
        u16* row = hg + (size_t)(baseE + gm) * MDIM + n0;
#pragma unroll
        for (int fn = 0; fn < 4; ++fn) {
          int col = wn + fn * 16 + lr;
          float a = accg[fm][fn][rr] + bge[col];
          float h1 = acc1[fm][fn][rr] + b1e[col];
          float v = a / (1.f + __expf(-a)) * h1 * w;
          row[col] = f2bf(v);
        }
      }
    }
  }
}

// ---------------- down-proj: out += hg * W2t, split-K=2, atomic scatter ----------------
__global__ __launch_bounds__(256) void gemm_down_kernel(
    const u16* __restrict__ hg, const u16* __restrict__ W2t,
    const int* __restrict__ tok_c, const int* __restrict__ basev,
    const int* __restrict__ cnt, float* __restrict__ out) {
  int b = blockIdx.x;
  int nt = b & 7, sk = (b >> 3) & 1, tt = (b >> 4) & 15, e = b >> 8;
  int cntE = cnt[e];
  int m0 = tt * 128;
  if (m0 >= cntE) return;
  int baseE = basev[e];
  int n0 = nt * 128;

  __shared__ u16 Al[128 * 64];
  __shared__ u16 Bl[128 * 64];

  int tid = threadIdx.x;
  int lane = tid & 63, wid = tid >> 6;
  int wm = (wid >> 1) * 64, wn = (wid & 1) * 64;
  int q = lane >> 4, lr = lane & 15;

  const u16* W2e = W2t + (size_t)e * DIM * MDIM;

  u32 aoff[4], boff[4];
  int sseg = tid & 7;
#pragma unroll
  for (int i = 0; i < 4; ++i) {
    int r = (i * 256 + tid) >> 3;
    int c = sseg ^ (r & 7);
    int gm = m0 + r; if (gm >= cntE) gm = cntE - 1;
    aoff[i] = (u32)((((baseE + gm) * MDIM) + c * 8) * 2);
    boff[i] = (u32)(((n0 + r) * MDIM + c * 8) * 2);
  }

  f32x4 acc[4][4];
#pragma unroll
  for (int i = 0; i < 4; ++i)
#pragma unroll
    for (int j = 0; j < 4; ++j) acc[i][j] = (f32x4){0,0,0,0};

  int kend = sk * 2048 + 2048;
  for (int k0 = sk * 2048; k0 < kend; k0 += 64) {
    __syncthreads();
#pragma unroll
    for (int i = 0; i < 4; ++i) {
      int ldso = i * 2048 + tid * 8;
      async_copy16((const char*)hg + aoff[i] + k0 * 2, &Al[ldso]);
      async_copy16((const char*)W2e + boff[i] + k0 * 2, &Bl[ldso]);
    }
    __syncthreads();
#pragma unroll
    for (int ks = 0; ks < 64; ks += 32) {
      short8 af[4], bf[4];
      int j = (ks >> 3) + q;
#pragma unroll
      for (int f = 0; f < 4; ++f) {
        int r = wm + f * 16 + lr;
        af[f] = *(const short8*)&Al[r * 64 + ((j ^ (r & 7)) * 8)];
      }
#pragma unroll
      for (int f = 0; f < 4; ++f) {
        int r = wn + f * 16 + lr;
        bf[f] = *(const short8*)&Bl[r * 64 + ((j ^ (r & 7)) * 8)];
      }
#pragma unroll
      for (int fm = 0; fm < 4; ++fm)
#pragma unroll
        for (int fn = 0; fn < 4; ++fn)
          acc[fm][fn] = __builtin_amdgcn_mfma_f32_16x16x32_bf16(af[fm], bf[fn], acc[fm][fn], 0, 0, 0);
    }
  }

#pragma unroll
  for (int fm = 0; fm < 4; ++fm) {
#pragma unroll
    for (int rr = 0; rr < 4; ++rr) {
      int lm = wm + fm * 16 + q * 4 + rr;
      int gm = m0 + lm;
      if (gm < cntE) {
        int tok = tok_c[baseE + gm];
        float* orow = out + (size_t)tok * DIM + n0;
#pragma unroll
        for (int fn = 0; fn < 4; ++fn) {
          int col = wn + fn * 16 + lr;
          atomicAdd(&orow[col], acc[fm][fn][rr]);
        }
      }
    }
  }
}

// ================= fallback path (round-1 kernels, small ws) =================
__global__ __launch_bounds__(256) void gemm12_kernel(
    const u16* __restrict__ xb, const float* __restrict__ W,
    const float* __restrict__ bias, const int* __restrict__ tok_c,
    const int* __restrict__ basev, const int* __restrict__ cnt,
    u16* __restrict__ hg, int mode) {
  int b = blockIdx.x;
  int nt = b & 31, tt = (b >> 5) & 15, e = b >> 9;
  int cntE = cnt[e];
  int m0 = tt * 128;
  if (m0 >= cntE) return;
  int baseE = basev[e];
  int n0 = nt * 128;
  const float* We = W + (size_t)e * DIM * MDIM;
  __shared__ u16 Al[128 * 72];
  __shared__ u16 Bl[128 * 72];
  int tid = threadIdx.x;
  int lane = tid & 63, wid = tid >> 6;
  int wm = (wid >> 1) * 64, wn = (wid & 1) * 64;
  int q = lane >> 4, lr = lane & 15;
  f32x4 acc[4][4];
#pragma unroll
  for (int i = 0; i < 4; ++i)
#pragma unroll
    for (int j = 0; j < 4; ++j) acc[i][j] = (f32x4){0.f, 0.f, 0.f, 0.f};
  const u16* arow[4];
  int ack[4];
#pragma unroll
  for (int i = 0; i < 4; ++i) {
    int c = i * 256 + tid;
    int r = c >> 3, ck = c & 7;
    int gm = m0 + r;
    int src = baseE + (gm < cntE ? gm : cntE - 1);
    arow[i] = xb + (size_t)tok_c[src] * DIM + ck * 8;
    ack[i] = r * 72 + ck * 8;
  }
  for (int k0 = 0; k0 < DIM; k0 += 64) {
    __syncthreads();
#pragma unroll
    for (int i = 0; i < 4; ++i)
      *(i32x4*)&Al[ack[i]] = *(const i32x4*)(arow[i] + k0);
#pragma unroll 4
    for (int i = 0; i < 16; ++i) {
      int w = i * 256 + tid;
      int n = w & 127, kk = (w >> 7) * 2;
      const float* src = We + (size_t)(k0 + kk) * MDIM + n0 + n;
      float f0 = src[0], f1 = src[MDIM];
      *(u32*)&Bl[n * 72 + kk] = (u32)f2bf(f0) | ((u32)f2bf(f1) << 16);
    }
    __syncthreads();
#pragma unroll
    for (int ks = 0; ks < 64; ks += 32) {
      short8 af[4], bf[4];
#pragma unroll
      for (int fm = 0; fm < 4; ++fm)
        af[fm] = *(const short8*)&Al[(wm + fm * 16 + lr) * 72 + ks + q * 8];
#pragma unroll
      for (int fn = 0; fn < 4; ++fn)
        bf[fn] = *(const short8*)&Bl[(wn + fn * 16 + lr) * 72 + ks + q * 8];
#pragma unroll
      for (int fm = 0; fm < 4; ++fm)
#pragma unroll
        for (int fn = 0; fn < 4; ++fn)
          acc[fm][fn] = __builtin_amdgcn_mfma_f32_16x16x32_bf16(af[fm], bf[fn], acc[fm][fn], 0, 0, 0);
    }
  }
  const float* be = bias + (size_t)e * MDIM + n0;
#pragma unroll
  for (int fm = 0; fm < 4; ++fm) {
#pragma unroll
    for (int r = 0; r < 4; ++r) {
      int lm = wm + fm * 16 + q * 4 + r;
      int gm = m0 + lm;
      if (gm < cntE) {
        u16* row = hg + (size_t)(baseE + gm) * MDIM + n0;
#pragma unroll
        for (int fn = 0; fn < 4; ++fn) {
          int col = wn + fn * 16 + lr;
          float v = acc[fm][fn][r] + be[col];
          if (mode == 0) {
            v = v / (1.f + __expf(-v));
            row[col] = f2bf(v);
          } else {
            row[col] = f2bf(bf2f(row[col]) * v);
          }
        }
      }
    }
  }
}

__global__ __launch_bounds__(256) void gemm3_kernel(
    const u16* __restrict__ hg, const float* __restrict__ W2,
    const float* __restrict__ b2, const int* __restrict__ tok_c,
    const float* __restrict__ w_c, const int* __restrict__ basev,
    const int* __restrict__ cnt, float* __restrict__ out) {
  int b = blockIdx.x;
  int nt = b & 7, tt = (b >> 3) & 31, e = b >> 8;
  int cntE = cnt[e];
  int m0 = tt * 64;
  if (m0 >= cntE) return;
  int baseE = basev[e];
  int n0 = nt * 128;
  const float* We = W2 + (size_t)e * MDIM * DIM;
  __shared__ u16 Al[64 * 72];
  __shared__ u16 Bl[128 * 72];
  int tid = threadIdx.x;
  int lane = tid & 63, wid = tid >> 6;
  int wm = (wid >> 1) * 32, wn = (wid & 1) * 64;
  int q = lane >> 4, lr = lane & 15;
  f32x4 acc[2][4];
#pragma unroll
  for (int i = 0; i < 2; ++i)
#pragma unroll
    for (int j = 0; j < 4; ++j) acc[i][j] = (f32x4){0.f, 0.f, 0.f, 0.f};
  const u16* arow[2];
  int ack[2];
#pragma unroll
  for (int i = 0; i < 2; ++i) {
    int c = i * 256 + tid;
    int r = c >> 3, ck = c & 7;
    int gm = m0 + r;
    int src = baseE + (gm < cntE ? gm : cntE - 1);
    arow[i] = hg + (size_t)src * MDIM + ck * 8;
    ack[i] = r * 72 + ck * 8;
  }
  for (int k0 = 0; k0 < MDIM; k0 += 64) {
    __syncthreads();
#pragma unroll
    for (int i = 0; i < 2; ++i)
      *(i32x4*)&Al[ack[i]] = *(const i32x4*)(arow[i] + k0);
#pragma unroll 4
    for (int i = 0; i < 16; ++i) {
      int w = i * 256 + tid;
      int n = w & 127, kk = (w >> 7) * 2;
      const float* src = We + (size_t)(k0 + kk) * DIM + n0 + n;
      float f0 = src[0], f1 = src[DIM];
      *(u32*)&Bl[n * 72 + kk] = (u32)f2bf(f0) | ((u32)f2bf(f1) << 16);
    }
    __syncthreads();
#pragma unroll
    for (int ks = 0; ks < 64; ks += 32) {
      short8 af[2], bf[4];
#pragma unroll
      for (int fm = 0; fm < 2; ++fm)
        af[fm] = *(const short8*)&Al[(wm + fm * 16 + lr) * 72 + ks + q * 8];
#pragma unroll
      for (int fn = 0; fn < 4; ++fn)
        bf[fn] = *(const short8*)&Bl[(wn + fn * 16 + lr) * 72 + ks + q * 8];
#pragma unroll
      for (int fm = 0; fm < 2; ++fm)
#pragma unroll
        for (int fn = 0; fn < 4; ++fn)
          acc[fm][fn] = __builtin_amdgcn_mfma_f32_16x16x32_bf16(af[fm], bf[fn], acc[fm][fn], 0, 0, 0);
    }
  }
  const float* be = b2 + (size_t)e * DIM + n0;
#pragma unroll
  for (int fm = 0; fm < 2; ++fm) {
#pragma unroll
    for (int r = 0; r < 4; ++r) {
      int lm = wm + fm * 16 + q * 4 + r;
      int gm = m0 + lm;
      if (gm < cntE) {
        float wgt = w_c[baseE + gm];
        int tok = tok_c[baseE + gm];
        float* orow = out + (size_t)tok * DIM + n0;
#pragma unroll
        for (int fn = 0; fn < 4; ++fn) {
          int col = wn + fn * 16 + lr;
          atomicAdd(&orow[col], wgt * (acc[fm][fn][r] + be[col]));
        }
      }
    }
  }
}

extern "C" void kernel_launch(void* const* d_in, const int* in_sizes, int n_in,
                              void* d_out, int out_size, void* d_ws, size_t ws_size,
                              hipStream_t stream) {
  const float* x     = (const float*)d_in[0];
  const float* Wgate = (const float*)d_in[1];
  const float* bgate = (const float*)d_in[2];
  const float* Wg    = (const float*)d_in[3];
  const float* bg    = (const float*)d_in[4];
  const float* W1    = (const float*)d_in[5];
  const float* b1    = (const float*)d_in[6];
  const float* W2    = (const float*)d_in[7];
  const float* b2    = (const float*)d_in[8];
  float* out = (float*)d_out;
  char* ws = (char*)d_ws;

  if (ws_size >= 172500000ULL) {
    // fast path: bf16-transposed weights + async-staged MFMA GEMMs
    u16*   xb  = (u16*)(ws + 0);            // 4 MB
    u16*   hg  = (u16*)(ws + 4194304);      // 32 MB
    u16*   Wgt = (u16*)(ws + 37748736);     // 64 MB
    u16*   W1t = (u16*)(ws + 104857600);    // 64 MB
    u16*   W2t = Wgt;                        // alias: Wgt dead after gemm_up
    char*  sm  = ws + 171966464;
    int*   tokc  = (int*)(sm);
    float* wc    = (float*)(sm + 16384);
    int*   ltok  = (int*)(sm + 32768);
    float* lw    = (float*)(sm + 98304);
    int*   tki   = (int*)(sm + 163840);
    float* tkw   = (float*)(sm + 180224);
    int*   cnt   = (int*)(sm + 196608);
    int*   basev = (int*)(sm + 196640);

    hipMemsetAsync(cnt, 0, 64, stream);
    cvt_x_kernel<<<2048, 256, 0, stream>>>((const float4*)x, (uint2*)xb);
    gate_kernel<<<SEQ, 256, 0, stream>>>(x, Wgate, bgate, ltok, lw, cnt, tki, tkw);
    scan_kernel<<<1, 64, 0, stream>>>(cnt, basev);
    compact_kernel<<<NEXP, 256, 0, stream>>>(cnt, basev, ltok, lw, tokc, wc);
    wconv_kernel<<<16384, 256, 0, stream>>>(Wg, Wgt, DIM, 12, 19);   // [D][M] -> [M][D]
    wconv_kernel<<<16384, 256, 0, stream>>>(W1, W1t, DIM, 12, 19);
    outinit_kernel<<<SEQ, 256, 0, stream>>>(tki, tkw, b2, out);
    gemm_up_kernel<<<NEXP * 16 * 32, 256, 0, stream>>>(xb, Wgt, W1t, bg, b1, tokc, wc, basev, cnt, hg);
    wconv_kernel<<<16384, 256, 0, stream>>>(W2, W2t, MDIM, 10, 19);  // [M][D] -> [D][M]
    gemm_down_kernel<<<NEXP * 16 * 2 * 8, 256, 0, stream>>>(hg, W2t, tokc, basev, cnt, out);
  } else {
    // fallback: round-1 path (~38 MB ws)
    u16*   xb    = (u16*)(ws + 0);
    u16*   hg    = (u16*)(ws + 4194304);
    int*   tokc  = (int*)(ws + 37748736);
    float* wc    = (float*)(ws + 37765120);
    int*   ltok  = (int*)(ws + 37781504);
    float* lw    = (float*)(ws + 37847040);
    int*   cnt   = (int*)(ws + 37912576);
    int*   basev = (int*)(ws + 37912608);
    int*   tki   = (int*)(ws + 37912640);
    float* tkw   = (float*)(ws + 37929024);

    hipMemsetAsync(out, 0, (size_t)out_size * sizeof(float), stream);
    hipMemsetAsync(cnt, 0, 64, stream);
    cvt_x_kernel<<<2048, 256, 0, stream>>>((const float4*)x, (uint2*)xb);
    gate_kernel<<<SEQ, 256, 0, stream>>>(x, Wgate, bgate, ltok, lw, cnt, tki, tkw);
    scan_kernel<<<1, 64, 0, stream>>>(cnt, basev);
    compact_kernel<<<NEXP, 256, 0, stream>>>(cnt, basev, ltok, lw, tokc, wc);
    gemm12_kernel<<<NEXP * 16 * 32, 256, 0, stream>>>(xb, Wg, bg, tokc, basev, cnt, hg, 0);
    gemm12_kernel<<<NEXP * 16 * 32, 256, 0, stream>>>(xb, W1, b1, tokc, basev, cnt, hg, 1);
    gemm3_kernel<<<NEXP * 32 * 8, 256, 0, stream>>>(hg, W2, b2, tokc, wc, basev, cnt, out);
  }
}